// Round 1
// 180.897 us; speedup vs baseline: 1.0014x; 1.0014x over previous
//
#include <hip/hip_runtime.h>

typedef unsigned short u16;
typedef unsigned int   u32;
typedef short bf8 __attribute__((ext_vector_type(8)));   // 8 bf16 payloads (4 VGPRs)
typedef float f4  __attribute__((ext_vector_type(4)));   // MFMA accumulator

#define NB   512
#define NJ   101
#define NM   50
#define NE   128
#define ND   60
#define NP   5120
#define NT   1024
#define EPSV 1e-6f

// ---- LDS arena (byte offsets) ----
#define U_B    0         // u bf16 [64][136] = 17408  (staged coalesced, zero-padded)
#define T_B    17408     // tp -> attn bf16 [112][72] = 16128
#define C_B    33536     // cp bf16 [64][72] = 9216
#define H_B    42752     // hT bf16 [128][72] = 18432  (hT[e][m])
#define NT2_B  61184     // f32[112] sum tp^2
#define NC2_B  61632     // f32[64]  sum cp^2
#define MSK_B  61888     // int[64]
#define ARENA  62144

__device__ __forceinline__ u16 f2bh(float f) {
    return (u16)((__float_as_uint(f) + 0x8000u) >> 16);
}
__device__ __forceinline__ u32 pk2(float a, float b) {
    u32 ia = __float_as_uint(a) + 0x8000u;
    u32 ib = __float_as_uint(b) + 0x8000u;
    return (ia >> 16) | (ib & 0xFFFF0000u);
}
__device__ __forceinline__ bf8 pkfrag(float4 x, float4 y) {   // 8 f32 -> bf16 frag
    union { u32 u[4]; bf8 v; } r;
    r.u[0] = pk2(x.x, x.y); r.u[1] = pk2(x.z, x.w);
    r.u[2] = pk2(y.x, y.y); r.u[3] = pk2(y.z, y.w);
    return r.v;
}

// ===== Kernel A: W2T[e][k] = (R@Bc)[e][k]; rb2[e] = Bc_b.R[e] + R_b[e];
//       plus bf16 pre-conversion of At_w / Ac_w =====
__global__ __launch_bounds__(128) void w2_kernel(
    const float* __restrict__ Bc_w, const float* __restrict__ Bc_b,
    const float* __restrict__ R_w,  const float* __restrict__ R_b,
    const float* __restrict__ At_w, const float* __restrict__ Ac_w,
    u16* __restrict__ w2t, float* __restrict__ rb2,
    u16* __restrict__ atw, u16* __restrict__ acw)
{
    const int e = blockIdx.x, k = threadIdx.x;
    const float* Rrow = R_w + e * NE;
    float a0 = 0.f, a1 = 0.f, a2 = 0.f, a3 = 0.f;   // 4 independent chains
    #pragma unroll 8
    for (int j = 0; j < NE; j += 4) {
        a0 += Rrow[j]     * Bc_w[j * NE + k];
        a1 += Rrow[j + 1] * Bc_w[(j + 1) * NE + k];
        a2 += Rrow[j + 2] * Bc_w[(j + 2) * NE + k];
        a3 += Rrow[j + 3] * Bc_w[(j + 3) * NE + k];
    }
    w2t[e * NE + k] = f2bh((a0 + a1) + (a2 + a3));
    if (e < ND) {
        atw[e * NE + k] = f2bh(At_w[e * NE + k]);
        acw[e * NE + k] = f2bh(Ac_w[e * NE + k]);
    }
    float c = Bc_b[k] * Rrow[k];
    for (int o = 32; o; o >>= 1) c += __shfl_xor(c, o, 64);
    __shared__ float part[2];
    if ((k & 63) == 0) part[k >> 6] = c;
    __syncthreads();
    if (k == 0) rb2[e] = part[0] + part[1] + R_b[e];
}

// hT unit h (0..31): hT[e-tile et][m-tile mt] = W2T . u^T
__device__ __forceinline__ void ht_unit(int h, int l15, int quad,
    const u16* __restrict__ us16, const u16* __restrict__ w2t,
    u16* __restrict__ hT16)
{
    const int et = h >> 2, mt = h & 3;
    const u16* wrow = w2t + (size_t)(et * 16 + l15) * NE;
    bf8 U[4];
    #pragma unroll
    for (int ks = 0; ks < 4; ks++)
        U[ks] = *(const bf8*)(us16 + (mt * 16 + l15) * 136 + ks * 32 + quad * 8);
    f4 acc = {0.f, 0.f, 0.f, 0.f};
    #pragma unroll
    for (int ks = 0; ks < 4; ks++)
        acc = __builtin_amdgcn_mfma_f32_16x16x32_bf16(
            *(const bf8*)(wrow + ks * 32 + quad * 8), U[ks], acc, 0, 0, 0);
    const int e0 = et * 16 + quad * 4;
    #pragma unroll
    for (int r = 0; r < 4; r++)
        hT16[(e0 + r) * 72 + mt * 16 + l15] = f2bh(acc[r]);
}

// ===== Kernel B: per-batch fused attention, 16 waves/block =====
__global__ __launch_bounds__(NT, 8) void aitv_kernel(
    const int* __restrict__ titems, const int* __restrict__ citems,
    const int* __restrict__ pad_ids,
    const float* __restrict__ t_emb, const float* __restrict__ c_emb,
    const u16* __restrict__ atw,     const float* __restrict__ At_b,
    const u16* __restrict__ acw,     const float* __restrict__ Ac_b,
    const u16* __restrict__ w2t,     const float* __restrict__ rb2g,
    float* __restrict__ out)
{
    const int b    = blockIdx.x;
    const int t    = threadIdx.x;
    const int wid  = t >> 6;          // 0..15
    const int lane = t & 63;
    const int l15  = lane & 15;
    const int quad = lane >> 4;

    __shared__ __align__(16) char arena[ARENA];
    u16*   us16 = (u16*)(arena + U_B);   u32* us32 = (u32*)(arena + U_B);
    u16*   tp16 = (u16*)(arena + T_B);   u16* at16 = (u16*)(arena + T_B);
    u16*   cp16 = (u16*)(arena + C_B);
    u16*   hT16 = (u16*)(arena + H_B);
    float* nt2  = (float*)(arena + NT2_B);
    float* nc2  = (float*)(arena + NC2_B);
    int*   msk  = (int*)(arena + MSK_B);

    // ===== Prefetch: tp waves (wid<14) issue their t_emb row-gathers NOW, so
    // the random-gather latency hides under the u-staging phase. =====
    float4 px[8];
    const int jt_w = wid >> 1;                     // tp tile for this wave
    if (wid < 14) {
        int j = jt_w * 16 + l15; if (j > NJ - 1) j = NJ - 1;
        const float* vrow = t_emb + (size_t)titems[b * NJ + j] * NE + quad * 8;
        #pragma unroll
        for (int ks = 0; ks < 4; ks++) {
            px[2 * ks]     = *(const float4*)(vrow + ks * 32);
            px[2 * ks + 1] = *(const float4*)(vrow + ks * 32 + 4);
        }
    }

    // ===== P0: stage u coalesced (bf16, rows>=50 zero); zero accs + mask =====
    #pragma unroll
    for (int i = 0; i < 4; i++) {
        int row = wid + i * 16;                    // wave-uniform row
        u32 val = 0;
        if (row < NM) {
            int idx = citems[b * NM + row];
            float2 x = *(const float2*)(c_emb + (size_t)idx * NE + 2 * lane);
            val = pk2(x.x, x.y);
        }
        us32[row * 68 + lane] = val;
    }
    if (t < 112) nt2[t] = 0.f;
    else if (t < 176) nc2[t - 112] = 0.f;
    else if (t < 240) msk[t - 176] = 0;

    // convert prefetched rows to MFMA A-fragments (waits on own loads only)
    bf8 A[4];
    if (wid < 14) {
        #pragma unroll
        for (int ks = 0; ks < 4; ks++) A[ks] = pkfrag(px[2 * ks], px[2 * ks + 1]);
    }
    __syncthreads();

    // ===== P1: pad scan + 36 units: 14 tp-halves, 8 cp-halves, hT 0..13 =====
    for (int i = t; i < NP; i += NT)
        if (pad_ids[i] == b) msk[pad_ids[NP + i]] = 1;

    for (int g = wid; g < 36; g += 16) {
        if (g < 14) {
            // --- tp half-unit: jt = g>>1, dt in {d0, d0+1}; A prefetched ---
            const int jt = g >> 1;
            const int d0 = (g & 1) * 2;
            #pragma unroll
            for (int dt2 = 0; dt2 < 2; dt2++) {
                const int dt = d0 + dt2;
                const int d = dt * 16 + l15;
                const u16* arow = atw + (size_t)((d < ND) ? d : 0) * NE;
                float bv = (d < ND) ? At_b[d] : 0.f;
                f4 acc = {bv, bv, bv, bv};
                #pragma unroll
                for (int ks = 0; ks < 4; ks++)
                    acc = __builtin_amdgcn_mfma_f32_16x16x32_bf16(
                        A[ks], *(const bf8*)(arow + ks * 32 + quad * 8), acc, 0, 0, 0);
                const int j0 = jt * 16 + quad * 4;
                #pragma unroll
                for (int r = 0; r < 4; r++) {
                    float v = acc[r];
                    tp16[(j0 + r) * 72 + d] = (d < ND) ? f2bh(v) : (u16)0;
                    float q = (d < ND) ? v * v : 0.f;
                    q += __shfl_xor(q, 1, 64); q += __shfl_xor(q, 2, 64);
                    q += __shfl_xor(q, 4, 64); q += __shfl_xor(q, 8, 64);
                    if (l15 == 0) atomicAdd(&nt2[j0 + r], q);
                }
            }
        } else if (g < 22) {
            // --- cp half-unit: c = g-14; u-frags from LDS; bf16 weights from L2 ---
            const int c  = g - 14;
            const int mt = c >> 1;
            const int d0 = (c & 1) * 2;
            bf8 U[4];
            #pragma unroll
            for (int ks = 0; ks < 4; ks++)
                U[ks] = *(const bf8*)(us16 + (mt * 16 + l15) * 136 + ks * 32 + quad * 8);
            #pragma unroll
            for (int dt2 = 0; dt2 < 2; dt2++) {
                const int dt = d0 + dt2;
                const int d = dt * 16 + l15;
                const u16* arow = acw + (size_t)((d < ND) ? d : 0) * NE;
                float bv = (d < ND) ? Ac_b[d] : 0.f;
                f4 acc = {bv, bv, bv, bv};
                #pragma unroll
                for (int ks = 0; ks < 4; ks++)
                    acc = __builtin_amdgcn_mfma_f32_16x16x32_bf16(
                        U[ks], *(const bf8*)(arow + ks * 32 + quad * 8), acc, 0, 0, 0);
                const int m0 = mt * 16 + quad * 4;
                #pragma unroll
                for (int r = 0; r < 4; r++) {
                    float v = acc[r];
                    cp16[(m0 + r) * 72 + d] = (d < ND) ? f2bh(v) : (u16)0;
                    float q = (d < ND) ? v * v : 0.f;
                    q += __shfl_xor(q, 1, 64); q += __shfl_xor(q, 2, 64);
                    q += __shfl_xor(q, 4, 64); q += __shfl_xor(q, 8, 64);
                    if (l15 == 0) atomicAdd(&nc2[m0 + r], q);
                }
            }
        } else {
            // --- hT units 0..13 (independent of P1 outputs: only need us16+w2t) ---
            ht_unit(g - 22, l15, quad, us16, w2t, hT16);
        }
    }
    __syncthreads();

    // ===== P2: scores/softmax (waves 0..6) || hT units 14..31 (waves 7..15) =====
    if (wid >= 7) {
        #pragma unroll
        for (int k2 = 0; k2 < 2; k2++)
            ht_unit(14 + (wid - 7) * 2 + k2, l15, quad, us16, w2t, hT16);
    } else {
        const int jt = wid;
        f4 S[4];
        #pragma unroll
        for (int mt = 0; mt < 4; mt++) {
            f4 acc = {0.f, 0.f, 0.f, 0.f};
            #pragma unroll
            for (int ks = 0; ks < 2; ks++) {
                bf8 a  = *(const bf8*)(tp16 + (jt * 16 + l15) * 72 + ks * 32 + quad * 8);
                bf8 bb = *(const bf8*)(cp16 + (mt * 16 + l15) * 72 + ks * 32 + quad * 8);
                acc = __builtin_amdgcn_mfma_f32_16x16x32_bf16(a, bb, acc, 0, 0, 0);
            }
            S[mt] = acc;
        }
        bool valid[4]; float ncS[4];
        #pragma unroll
        for (int mt = 0; mt < 4; mt++) {
            int m = mt * 16 + l15;
            valid[mt] = (m < NM) && (msk[m] == 0);
            ncS[mt]   = valid[mt] ? fmaxf(sqrtf(nc2[m]), EPSV) : 1.f;
        }
        #pragma unroll
        for (int r = 0; r < 4; r++) {
            int j = jt * 16 + quad * 4 + r;
            float ntj = fmaxf(sqrtf(nt2[j]), EPSV);
            float x[4], mx = -INFINITY;
            #pragma unroll
            for (int mt = 0; mt < 4; mt++) {
                x[mt] = valid[mt] ? S[mt][r] / (ntj * ncS[mt]) : -INFINITY;
                mx = fmaxf(mx, x[mt]);
            }
            mx = fmaxf(mx, __shfl_xor(mx, 1, 64)); mx = fmaxf(mx, __shfl_xor(mx, 2, 64));
            mx = fmaxf(mx, __shfl_xor(mx, 4, 64)); mx = fmaxf(mx, __shfl_xor(mx, 8, 64));
            float p[4], sm = 0.f;
            #pragma unroll
            for (int mt = 0; mt < 4; mt++) {
                p[mt] = valid[mt] ? __expf(x[mt] - mx) : 0.f;
                sm += p[mt];
            }
            sm += __shfl_xor(sm, 1, 64); sm += __shfl_xor(sm, 2, 64);
            sm += __shfl_xor(sm, 4, 64); sm += __shfl_xor(sm, 8, 64);
            float inv = (sm > 0.f) ? 1.f / sm : 0.f;
            #pragma unroll
            for (int mt = 0; mt < 4; mt++)
                at16[j * 72 + mt * 16 + l15] = f2bh(p[mt] * inv);
        }
    }
    __syncthreads();

    // ===== P3: out = attn @ hT^T + rb2 -> global f32 (56 units) =====
    for (int u = wid; u < 56; u += 16) {           // jt 0..6 x et 0..7, K=64
        int jt = u >> 3, et = u & 7;
        float bv = rb2g[et * 16 + l15];
        f4 acc = {bv, bv, bv, bv};
        #pragma unroll
        for (int ks = 0; ks < 2; ks++) {
            bf8 a  = *(const bf8*)(at16 + (jt * 16 + l15) * 72 + ks * 32 + quad * 8);
            bf8 bb = *(const bf8*)(hT16 + (et * 16 + l15) * 72 + ks * 32 + quad * 8);
            acc = __builtin_amdgcn_mfma_f32_16x16x32_bf16(a, bb, acc, 0, 0, 0);
        }
        int e = et * 16 + l15, j0 = jt * 16 + quad * 4;
        #pragma unroll
        for (int r = 0; r < 4; r++) {
            int j = j0 + r;
            if (j < NJ) out[((size_t)b * NJ + j) * NE + e] = acc[r];
        }
    }
}

extern "C" void kernel_launch(void* const* d_in, const int* in_sizes, int n_in,
                              void* d_out, int out_size, void* d_ws, size_t ws_size,
                              hipStream_t stream) {
    const int*   titems  = (const int*)d_in[0];
    const int*   citems  = (const int*)d_in[1];
    const int*   pad_ids = (const int*)d_in[2];
    const float* t_emb   = (const float*)d_in[3];
    const float* c_emb   = (const float*)d_in[4];
    const float* Ac_w    = (const float*)d_in[5];
    const float* Ac_b    = (const float*)d_in[6];
    const float* At_w    = (const float*)d_in[7];
    const float* At_b    = (const float*)d_in[8];
    const float* Bc_w    = (const float*)d_in[9];
    const float* Bc_b    = (const float*)d_in[10];
    const float* R_w     = (const float*)d_in[11];
    const float* R_b     = (const float*)d_in[12];
    float* out = (float*)d_out;

    u16*   w2t = (u16*)d_ws;                              // [128][128] bf16 = 32768B
    float* rb2 = (float*)((char*)d_ws + 32768);           // [128] f32 (512B)
    u16*   atw = (u16*)((char*)d_ws + 33280);             // [60][128] bf16 = 15360B
    u16*   acw = (u16*)((char*)d_ws + 48640);             // [60][128] bf16 = 15360B

    w2_kernel<<<NE, NE, 0, stream>>>(Bc_w, Bc_b, R_w, R_b, At_w, Ac_w,
                                     w2t, rb2, atw, acw);
    aitv_kernel<<<NB, NT, 0, stream>>>(titems, citems, pad_ids, t_emb, c_emb,
                                       atw, At_b, acw, Ac_b, w2t, rb2, out);
}

// Round 2
// 175.817 us; speedup vs baseline: 1.0303x; 1.0289x over previous
//
#include <hip/hip_runtime.h>

typedef unsigned short u16;
typedef unsigned int   u32;
typedef short bf8 __attribute__((ext_vector_type(8)));   // 8 bf16 payloads (4 VGPRs)
typedef float f4  __attribute__((ext_vector_type(4)));   // MFMA accumulator

#define NB   512
#define NJ   101
#define NM   50
#define NE   128
#define ND   60
#define NP   5120
#define NT   1024
#define EPSV 1e-6f

// ---- LDS arena (byte offsets) ----
#define U_B    0         // u bf16 [64][136] = 17408  (staged coalesced, zero-padded)
#define T_B    17408     // tp -> attn bf16 [112][72] = 16128
#define C_B    33536     // cp bf16 [64][72] = 9216
#define H_B    42752     // hT bf16 [128][72] = 18432  (hT[e][m])
#define NT2_B  61184     // f32[112] sum tp^2
#define NC2_B  61632     // f32[64]  sum cp^2
#define MSK_B  61888     // int[64]
#define ARENA  62144

__device__ __forceinline__ u16 f2bh(float f) {
    return (u16)((__float_as_uint(f) + 0x8000u) >> 16);
}
__device__ __forceinline__ u32 pk2(float a, float b) {
    u32 ia = __float_as_uint(a) + 0x8000u;
    u32 ib = __float_as_uint(b) + 0x8000u;
    return (ia >> 16) | (ib & 0xFFFF0000u);
}
__device__ __forceinline__ bf8 pkfrag(float4 x, float4 y) {   // 8 f32 -> bf16 frag
    union { u32 u[4]; bf8 v; } r;
    r.u[0] = pk2(x.x, x.y); r.u[1] = pk2(x.z, x.w);
    r.u[2] = pk2(y.x, y.y); r.u[3] = pk2(y.z, y.w);
    return r.v;
}

// ===== Kernel A: W2T[e][k] = (R@Bc)[e][k]; rb2[e] = Bc_b.R[e] + R_b[e];
//       plus bf16 pre-conversion of At_w / Ac_w =====
__global__ __launch_bounds__(128) void w2_kernel(
    const float* __restrict__ Bc_w, const float* __restrict__ Bc_b,
    const float* __restrict__ R_w,  const float* __restrict__ R_b,
    const float* __restrict__ At_w, const float* __restrict__ Ac_w,
    u16* __restrict__ w2t, float* __restrict__ rb2,
    u16* __restrict__ atw, u16* __restrict__ acw)
{
    const int e = blockIdx.x, k = threadIdx.x;
    const float* Rrow = R_w + e * NE;
    float a0 = 0.f, a1 = 0.f, a2 = 0.f, a3 = 0.f;   // 4 independent chains
    #pragma unroll 8
    for (int j = 0; j < NE; j += 4) {
        a0 += Rrow[j]     * Bc_w[j * NE + k];
        a1 += Rrow[j + 1] * Bc_w[(j + 1) * NE + k];
        a2 += Rrow[j + 2] * Bc_w[(j + 2) * NE + k];
        a3 += Rrow[j + 3] * Bc_w[(j + 3) * NE + k];
    }
    w2t[e * NE + k] = f2bh((a0 + a1) + (a2 + a3));
    if (e < ND) {
        atw[e * NE + k] = f2bh(At_w[e * NE + k]);
        acw[e * NE + k] = f2bh(Ac_w[e * NE + k]);
    }
    float c = Bc_b[k] * Rrow[k];
    for (int o = 32; o; o >>= 1) c += __shfl_xor(c, o, 64);
    __shared__ float part[2];
    if ((k & 63) == 0) part[k >> 6] = c;
    __syncthreads();
    if (k == 0) rb2[e] = part[0] + part[1] + R_b[e];
}

// hT unit h (0..31): hT[e-tile et][m-tile mt] = W2T . u^T
__device__ __forceinline__ void ht_unit(int h, int l15, int quad,
    const u16* __restrict__ us16, const u16* __restrict__ w2t,
    u16* __restrict__ hT16)
{
    const int et = h >> 2, mt = h & 3;
    const u16* wrow = w2t + (size_t)(et * 16 + l15) * NE;
    bf8 U[4];
    #pragma unroll
    for (int ks = 0; ks < 4; ks++)
        U[ks] = *(const bf8*)(us16 + (mt * 16 + l15) * 136 + ks * 32 + quad * 8);
    f4 acc = {0.f, 0.f, 0.f, 0.f};
    #pragma unroll
    for (int ks = 0; ks < 4; ks++)
        acc = __builtin_amdgcn_mfma_f32_16x16x32_bf16(
            *(const bf8*)(wrow + ks * 32 + quad * 8), U[ks], acc, 0, 0, 0);
    const int e0 = et * 16 + quad * 4;
    #pragma unroll
    for (int r = 0; r < 4; r++)
        hT16[(e0 + r) * 72 + mt * 16 + l15] = f2bh(acc[r]);
}

// ===== Kernel B: per-batch fused attention, 16 waves/block =====
// __launch_bounds__(1024, 2): empirically (R1 post-mortem) the 2nd arg acts
// like CUDA minBlocks -> VGPR cap = 131072/(1024*2) = 64. (1024,8) capped at
// 32 regs and spilled the prefetch to scratch (+37 MB WRITE_SIZE).
__global__ __launch_bounds__(NT, 2) void aitv_kernel(
    const int* __restrict__ titems, const int* __restrict__ citems,
    const int* __restrict__ pad_ids,
    const float* __restrict__ t_emb, const float* __restrict__ c_emb,
    const u16* __restrict__ atw,     const float* __restrict__ At_b,
    const u16* __restrict__ acw,     const float* __restrict__ Ac_b,
    const u16* __restrict__ w2t,     const float* __restrict__ rb2g,
    float* __restrict__ out)
{
    const int b    = blockIdx.x;
    const int t    = threadIdx.x;
    const int wid  = t >> 6;          // 0..15
    const int lane = t & 63;
    const int l15  = lane & 15;
    const int quad = lane >> 4;

    __shared__ __align__(16) char arena[ARENA];
    u16*   us16 = (u16*)(arena + U_B);   u32* us32 = (u32*)(arena + U_B);
    u16*   tp16 = (u16*)(arena + T_B);   u16* at16 = (u16*)(arena + T_B);
    u16*   cp16 = (u16*)(arena + C_B);
    u16*   hT16 = (u16*)(arena + H_B);
    float* nt2  = (float*)(arena + NT2_B);
    float* nc2  = (float*)(arena + NC2_B);
    int*   msk  = (int*)(arena + MSK_B);

    // ===== Prefetch round 1: tp waves (wid<14) gather first half of their
    // t_emb row (px[4] = 16 VGPRs, not 32 -> fits the 64-reg budget). =====
    float4 px[4];
    const float* vrow = t_emb;                     // harmless default
    const int jt_w = wid >> 1;
    if (wid < 14) {
        int j = jt_w * 16 + l15; if (j > NJ - 1) j = NJ - 1;
        vrow = t_emb + (size_t)titems[b * NJ + j] * NE + quad * 8;
        #pragma unroll
        for (int h = 0; h < 4; h++)
            px[h] = *(const float4*)(vrow + (h >> 1) * 32 + (h & 1) * 4);
    }

    // ===== P0a: stage u rows 0..31 (coalesced bf16) =====
    #pragma unroll
    for (int i = 0; i < 2; i++) {
        int row = wid + i * 16;                    // wave-uniform row
        u32 val = 0;
        if (row < NM) {
            int idx = citems[b * NM + row];
            float2 x = *(const float2*)(c_emb + (size_t)idx * NE + 2 * lane);
            val = pk2(x.x, x.y);
        }
        us32[row * 68 + lane] = val;
    }

    // convert half 1 (waits own loads only), issue prefetch round 2
    bf8 A[4];
    if (wid < 14) {
        A[0] = pkfrag(px[0], px[1]);
        A[1] = pkfrag(px[2], px[3]);
        #pragma unroll
        for (int h = 0; h < 4; h++)
            px[h] = *(const float4*)(vrow + 64 + (h >> 1) * 32 + (h & 1) * 4);
    }

    // ===== P0b: stage u rows 32..63 + zero accs/mask =====
    #pragma unroll
    for (int i = 2; i < 4; i++) {
        int row = wid + i * 16;
        u32 val = 0;
        if (row < NM) {
            int idx = citems[b * NM + row];
            float2 x = *(const float2*)(c_emb + (size_t)idx * NE + 2 * lane);
            val = pk2(x.x, x.y);
        }
        us32[row * 68 + lane] = val;
    }
    if (t < 112) nt2[t] = 0.f;
    else if (t < 176) nc2[t - 112] = 0.f;
    else if (t < 240) msk[t - 176] = 0;

    if (wid < 14) {
        A[2] = pkfrag(px[0], px[1]);
        A[3] = pkfrag(px[2], px[3]);
    }
    __syncthreads();

    // ===== P1: pad scan + 36 units: 14 tp-halves, 8 cp-halves, hT 0..13 =====
    for (int i = t; i < NP; i += NT)
        if (pad_ids[i] == b) msk[pad_ids[NP + i]] = 1;

    for (int g = wid; g < 36; g += 16) {
        if (g < 14) {
            // --- tp half-unit: jt = g>>1, dt in {d0, d0+1}; A prefetched ---
            const int jt = g >> 1;
            const int d0 = (g & 1) * 2;
            #pragma unroll
            for (int dt2 = 0; dt2 < 2; dt2++) {
                const int dt = d0 + dt2;
                const int d = dt * 16 + l15;
                const u16* arow = atw + (size_t)((d < ND) ? d : 0) * NE;
                float bv = (d < ND) ? At_b[d] : 0.f;
                f4 acc = {bv, bv, bv, bv};
                #pragma unroll
                for (int ks = 0; ks < 4; ks++)
                    acc = __builtin_amdgcn_mfma_f32_16x16x32_bf16(
                        A[ks], *(const bf8*)(arow + ks * 32 + quad * 8), acc, 0, 0, 0);
                const int j0 = jt * 16 + quad * 4;
                #pragma unroll
                for (int r = 0; r < 4; r++) {
                    float v = acc[r];
                    tp16[(j0 + r) * 72 + d] = (d < ND) ? f2bh(v) : (u16)0;
                    float q = (d < ND) ? v * v : 0.f;
                    q += __shfl_xor(q, 1, 64); q += __shfl_xor(q, 2, 64);
                    q += __shfl_xor(q, 4, 64); q += __shfl_xor(q, 8, 64);
                    if (l15 == 0) atomicAdd(&nt2[j0 + r], q);
                }
            }
        } else if (g < 22) {
            // --- cp half-unit: c = g-14; u-frags from LDS; bf16 weights from L2 ---
            const int c  = g - 14;
            const int mt = c >> 1;
            const int d0 = (c & 1) * 2;
            bf8 U[4];
            #pragma unroll
            for (int ks = 0; ks < 4; ks++)
                U[ks] = *(const bf8*)(us16 + (mt * 16 + l15) * 136 + ks * 32 + quad * 8);
            #pragma unroll
            for (int dt2 = 0; dt2 < 2; dt2++) {
                const int dt = d0 + dt2;
                const int d = dt * 16 + l15;
                const u16* arow = acw + (size_t)((d < ND) ? d : 0) * NE;
                float bv = (d < ND) ? Ac_b[d] : 0.f;
                f4 acc = {bv, bv, bv, bv};
                #pragma unroll
                for (int ks = 0; ks < 4; ks++)
                    acc = __builtin_amdgcn_mfma_f32_16x16x32_bf16(
                        U[ks], *(const bf8*)(arow + ks * 32 + quad * 8), acc, 0, 0, 0);
                const int m0 = mt * 16 + quad * 4;
                #pragma unroll
                for (int r = 0; r < 4; r++) {
                    float v = acc[r];
                    cp16[(m0 + r) * 72 + d] = (d < ND) ? f2bh(v) : (u16)0;
                    float q = (d < ND) ? v * v : 0.f;
                    q += __shfl_xor(q, 1, 64); q += __shfl_xor(q, 2, 64);
                    q += __shfl_xor(q, 4, 64); q += __shfl_xor(q, 8, 64);
                    if (l15 == 0) atomicAdd(&nc2[m0 + r], q);
                }
            }
        } else {
            // --- hT units 0..13 (independent of P1 outputs: only need us16+w2t) ---
            ht_unit(g - 22, l15, quad, us16, w2t, hT16);
        }
    }
    __syncthreads();

    // ===== P2: scores/softmax (waves 0..6) || hT units 14..31 (waves 7..15) =====
    if (wid >= 7) {
        #pragma unroll
        for (int k2 = 0; k2 < 2; k2++)
            ht_unit(14 + (wid - 7) * 2 + k2, l15, quad, us16, w2t, hT16);
    } else {
        const int jt = wid;
        f4 S[4];
        #pragma unroll
        for (int mt = 0; mt < 4; mt++) {
            f4 acc = {0.f, 0.f, 0.f, 0.f};
            #pragma unroll
            for (int ks = 0; ks < 2; ks++) {
                bf8 a  = *(const bf8*)(tp16 + (jt * 16 + l15) * 72 + ks * 32 + quad * 8);
                bf8 bb = *(const bf8*)(cp16 + (mt * 16 + l15) * 72 + ks * 32 + quad * 8);
                acc = __builtin_amdgcn_mfma_f32_16x16x32_bf16(a, bb, acc, 0, 0, 0);
            }
            S[mt] = acc;
        }
        bool valid[4]; float ncS[4];
        #pragma unroll
        for (int mt = 0; mt < 4; mt++) {
            int m = mt * 16 + l15;
            valid[mt] = (m < NM) && (msk[m] == 0);
            ncS[mt]   = valid[mt] ? fmaxf(sqrtf(nc2[m]), EPSV) : 1.f;
        }
        #pragma unroll
        for (int r = 0; r < 4; r++) {
            int j = jt * 16 + quad * 4 + r;
            float ntj = fmaxf(sqrtf(nt2[j]), EPSV);
            float x[4], mx = -INFINITY;
            #pragma unroll
            for (int mt = 0; mt < 4; mt++) {
                x[mt] = valid[mt] ? S[mt][r] / (ntj * ncS[mt]) : -INFINITY;
                mx = fmaxf(mx, x[mt]);
            }
            mx = fmaxf(mx, __shfl_xor(mx, 1, 64)); mx = fmaxf(mx, __shfl_xor(mx, 2, 64));
            mx = fmaxf(mx, __shfl_xor(mx, 4, 64)); mx = fmaxf(mx, __shfl_xor(mx, 8, 64));
            float p[4], sm = 0.f;
            #pragma unroll
            for (int mt = 0; mt < 4; mt++) {
                p[mt] = valid[mt] ? __expf(x[mt] - mx) : 0.f;
                sm += p[mt];
            }
            sm += __shfl_xor(sm, 1, 64); sm += __shfl_xor(sm, 2, 64);
            sm += __shfl_xor(sm, 4, 64); sm += __shfl_xor(sm, 8, 64);
            float inv = (sm > 0.f) ? 1.f / sm : 0.f;
            #pragma unroll
            for (int mt = 0; mt < 4; mt++)
                at16[j * 72 + mt * 16 + l15] = f2bh(p[mt] * inv);
        }
    }
    __syncthreads();

    // ===== P3: out = attn @ hT^T + rb2 -> global f32 (56 units) =====
    for (int u = wid; u < 56; u += 16) {           // jt 0..6 x et 0..7, K=64
        int jt = u >> 3, et = u & 7;
        float bv = rb2g[et * 16 + l15];
        f4 acc = {bv, bv, bv, bv};
        #pragma unroll
        for (int ks = 0; ks < 2; ks++) {
            bf8 a  = *(const bf8*)(at16 + (jt * 16 + l15) * 72 + ks * 32 + quad * 8);
            bf8 bb = *(const bf8*)(hT16 + (et * 16 + l15) * 72 + ks * 32 + quad * 8);
            acc = __builtin_amdgcn_mfma_f32_16x16x32_bf16(a, bb, acc, 0, 0, 0);
        }
        int e = et * 16 + l15, j0 = jt * 16 + quad * 4;
        #pragma unroll
        for (int r = 0; r < 4; r++) {
            int j = j0 + r;
            if (j < NJ) out[((size_t)b * NJ + j) * NE + e] = acc[r];
        }
    }
}

extern "C" void kernel_launch(void* const* d_in, const int* in_sizes, int n_in,
                              void* d_out, int out_size, void* d_ws, size_t ws_size,
                              hipStream_t stream) {
    const int*   titems  = (const int*)d_in[0];
    const int*   citems  = (const int*)d_in[1];
    const int*   pad_ids = (const int*)d_in[2];
    const float* t_emb   = (const float*)d_in[3];
    const float* c_emb   = (const float*)d_in[4];
    const float* Ac_w    = (const float*)d_in[5];
    const float* Ac_b    = (const float*)d_in[6];
    const float* At_w    = (const float*)d_in[7];
    const float* At_b    = (const float*)d_in[8];
    const float* Bc_w    = (const float*)d_in[9];
    const float* Bc_b    = (const float*)d_in[10];
    const float* R_w     = (const float*)d_in[11];
    const float* R_b     = (const float*)d_in[12];
    float* out = (float*)d_out;

    u16*   w2t = (u16*)d_ws;                              // [128][128] bf16 = 32768B
    float* rb2 = (float*)((char*)d_ws + 32768);           // [128] f32 (512B)
    u16*   atw = (u16*)((char*)d_ws + 33280);             // [60][128] bf16 = 15360B
    u16*   acw = (u16*)((char*)d_ws + 48640);             // [60][128] bf16 = 15360B

    w2_kernel<<<NE, NE, 0, stream>>>(Bc_w, Bc_b, R_w, R_b, At_w, Ac_w,
                                     w2t, rb2, atw, acw);
    aitv_kernel<<<NB, NT, 0, stream>>>(titems, citems, pad_ids, t_emb, c_emb,
                                       atw, At_b, acw, Ac_b, w2t, rb2, out);
}